// Round 3
// baseline (24788.223 us; speedup 1.0000x reference)
//
#include <hip/hip_runtime.h>
#include <cmath>

#define S_LEN 128
#define BATCH 32
#define HID   512
#define VOCAB 10000
#define MROWS (S_LEN * BATCH)   // 4096
#define HH    (HID * HID)

#define NBLK  64
#define NTHR  512

typedef float f32x4 __attribute__((ext_vector_type(4)));

// ---------------------------------------------------------------------------
// Tiled fp32 GEMM: C[M,N] = A[M,K] * B + bias[N]   (unchanged)
// ---------------------------------------------------------------------------
template<bool GATHER_A, bool B_KN>
__global__ __launch_bounds__(256) void gemm_kernel(
    const float* __restrict__ A, const int* __restrict__ tok,
    const float* __restrict__ Bmat, const float* __restrict__ bias,
    float* __restrict__ C, int M, int N, int K)
{
    __shared__ float As[32][68];
    __shared__ float Bs[32][68];
    __shared__ int   toks[64];

    const int tid = threadIdx.x;
    const int m0  = blockIdx.y * 64;
    const int n0  = blockIdx.x * 64;

    if (GATHER_A && tid < 64) toks[tid] = tok[m0 + tid];
    __syncthreads();

    const int tx = tid & 15;
    const int ty = tid >> 4;
    const int lr = tid >> 3;
    const int lc = (tid & 7) * 4;

    float acc[4][4] = {};

    for (int k0 = 0; k0 < K; k0 += 32) {
        #pragma unroll
        for (int rep = 0; rep < 2; rep++) {
            int r = lr + rep * 32;
            const float* arow;
            if (GATHER_A) arow = A + (size_t)toks[r] * K;
            else          arow = A + (size_t)(m0 + r) * K;
            float4 v = *(const float4*)(arow + k0 + lc);
            As[lc + 0][r] = v.x; As[lc + 1][r] = v.y;
            As[lc + 2][r] = v.z; As[lc + 3][r] = v.w;
        }
        if (B_KN) {
            int g    = n0 >> 9;
            int col0 = n0 & 511;
            const float* bbase = Bmat + (size_t)g * K * 512 + col0;
            int bc = (tid & 15) * 4;
            int bk = tid >> 4;
            #pragma unroll
            for (int rep = 0; rep < 2; rep++) {
                int kk = bk + rep * 16;
                float4 v = *(const float4*)(bbase + (size_t)(k0 + kk) * 512 + bc);
                *(float4*)&Bs[kk][bc] = v;
            }
        } else {
            #pragma unroll
            for (int rep = 0; rep < 2; rep++) {
                int r = lr + rep * 32;
                int n = n0 + r;
                float4 v = make_float4(0.f, 0.f, 0.f, 0.f);
                if (n < N) v = *(const float4*)(Bmat + (size_t)n * K + k0 + lc);
                Bs[lc + 0][r] = v.x; Bs[lc + 1][r] = v.y;
                Bs[lc + 2][r] = v.z; Bs[lc + 3][r] = v.w;
            }
        }
        __syncthreads();
        #pragma unroll
        for (int k = 0; k < 32; k++) {
            float4 a4 = *(const float4*)&As[k][ty * 4];
            float4 b4 = *(const float4*)&Bs[k][tx * 4];
            float av[4] = {a4.x, a4.y, a4.z, a4.w};
            float bv[4] = {b4.x, b4.y, b4.z, b4.w};
            #pragma unroll
            for (int i = 0; i < 4; i++)
                #pragma unroll
                for (int j = 0; j < 4; j++)
                    acc[i][j] = fmaf(av[i], bv[j], acc[i][j]);
        }
        __syncthreads();
    }
    #pragma unroll
    for (int i = 0; i < 4; i++) {
        int m = m0 + ty * 4 + i;
        #pragma unroll
        for (int j = 0; j < 4; j++) {
            int n = n0 + tx * 4 + j;
            if (n < N) C[(size_t)m * N + n] = acc[i][j] + bias[n];
        }
    }
}

// ---------------------------------------------------------------------------
// Agent-coherent (LLC-direct) access: sc1 bypasses the per-XCD L2.
// Caller must s_waitcnt vmcnt(0) before consuming ldg_coh_x4 results.
// ---------------------------------------------------------------------------
__device__ __forceinline__ f32x4 ldg_coh_x4(const float* p) {
    f32x4 r;
    asm volatile("global_load_dwordx4 %0, %1, off sc1"
                 : "=v"(r) : "v"(p) : "memory");
    return r;
}
__device__ __forceinline__ void stg_coh(float* p, float v) {
    asm volatile("global_store_dword %0, %1, off sc1"
                 :: "v"(p), "v"(v) : "memory");
}

// ---------------------------------------------------------------------------
// Contention-free device barrier: per-block monotonic flags, 64-lane poll.
// ---------------------------------------------------------------------------
__device__ __forceinline__ void flag_bar(unsigned* flags, int bid, unsigned target)
{
    asm volatile("s_waitcnt vmcnt(0)" ::: "memory");
    __syncthreads();
    if (threadIdx.x == 0)
        __hip_atomic_store(&flags[bid], target, __ATOMIC_RELEASE, __HIP_MEMORY_SCOPE_AGENT);
    if (threadIdx.x < NBLK) {
        while (__hip_atomic_load(&flags[threadIdx.x], __ATOMIC_RELAXED,
                                 __HIP_MEMORY_SCOPE_AGENT) < target)
            __builtin_amdgcn_s_sleep(1);
    }
    __syncthreads();
}

// ---------------------------------------------------------------------------
// Cooperative column-split GRU layer scan, v3 (b-fast layouts, regs weights).
// 64 blocks x 512 threads. Block owns 8 hidden columns ch0=bid*8:
//   P1: computes r AND z for those 8 cols (16 dot-cols), publishes only
//       v = r*h for its 8 k-slots into vT[512][32] (b fast).  z, h stay local.
//   P2: computes h_hat for its 8 cols from full v (staged from vT), blends,
//       publishes h into hxT[512][32] (b fast) + hseq (GEMM layout).
// Weights live in VGPRs (w1: 4x32, w2: 4x16 per thread). LDS xbuf is [k][b]
// so staging is a linear coalesced copy. Two flag barriers per step.
// ---------------------------------------------------------------------------
__global__ __launch_bounds__(NTHR) void scan_coop_kernel(
    const float* __restrict__ ax, const float* __restrict__ Ul,
    const float* __restrict__ h0g, float* __restrict__ hseq,
    float* __restrict__ hfin, float* __restrict__ vT,
    float* __restrict__ hxT, unsigned* __restrict__ flags)
{
    __shared__ float xbuf[512 * 32];   // 64 KB  [k][b]
    __shared__ float part[16 * 512];   // 32 KB  k-split partials (P1:16x512, P2:32x256)
    __shared__ float partR[2048];      //  8 KB  second-stage partials
    __shared__ float zbuf[8 * 33];
    __shared__ float hsave[8 * 33];
    __shared__ float hnbuf[8 * 33];

    const int tid = threadIdx.x;
    const int bid = blockIdx.x;
    const int ch0 = bid << 3;          // owned h-column base

    // P1 dot mapping: 8 b-quads x 4 c-tiles x 16 k-slices (32 k each)
    const int bt  = tid & 7;
    const int ct  = (tid >> 3) & 3;
    const int ks  = tid >> 5;          // 0..15
    // P2 dot mapping: 8 b-quads x 2 c-halves x 32 k-slices (16 k each)
    const int bt2 = tid & 7;
    const int cth = (tid >> 3) & 1;
    const int ks2 = tid >> 4;          // 0..31
    // reduce mapping
    const int rb  = tid & 31;
    const int rc  = tid >> 5;          // 0..15

    // ---- one-time: weights into registers ----
    float w1[4][32];
    {
        const int kb = ks * 32;
        #pragma unroll
        for (int i = 0; i < 4; i++) {
            const int c = ct + (i << 2);                    // 0..15
            const float* wp = Ul + (size_t)(c < 8 ? 0 : 1) * HH
                            + (size_t)kb * HID + ch0 + (c & 7);
            #pragma unroll
            for (int kk = 0; kk < 32; kk++) w1[i][kk] = wp[(size_t)kk * HID];
        }
    }
    float w2[4][16];
    {
        const int kb = ks2 * 16;
        #pragma unroll
        for (int i = 0; i < 4; i++) {
            const int c = (cth << 2) + i;                   // 0..7
            const float* wp = Ul + (size_t)2 * HH
                            + (size_t)kb * HID + ch0 + c;
            #pragma unroll
            for (int kk = 0; kk < 16; kk++) w2[i][kk] = wp[(size_t)kk * HID];
        }
    }

    // ---- prefill hxT with h0 (own slice), then global barrier ----
    if (tid < 256)
        stg_coh(hxT + (ch0 + rc) * 32 + rb, h0g[rb * HID + ch0 + rc]);
    unsigned bc = 1;
    flag_bar(flags, bid, bc); bc++;

    for (int t = 0; t < S_LEN; t++) {
        // ---- prefetch ax terms early (L2-cached, latency hidden) ----
        const size_t axrow = (size_t)((t << 5) + rb) * 1536;
        const float ax1 = ax[axrow + (rc < 8 ? ch0 + rc : 512 + ch0 + (rc - 8))];
        const float ax2 = (tid < 256) ? ax[axrow + 1024 + ch0 + rc] : 0.f;

        // ---- stage xbuf = h(t-1) from hxT (linear coalesced copy) ----
        {
            f32x4 ld[8];
            #pragma unroll
            for (int i = 0; i < 8; i++)
                ld[i] = ldg_coh_x4(hxT + (tid + i * NTHR) * 4);
            asm volatile("s_waitcnt vmcnt(0)" ::: "memory");
            #pragma unroll
            for (int i = 0; i < 8; i++)
                *(f32x4*)&xbuf[(tid + i * NTHR) * 4] = ld[i];
        }
        __syncthreads();

        // ---- P1 dot: r,z for 16 cols; 1 b128 read per 16 FMA ----
        {
            f32x4 a0 = {0.f,0.f,0.f,0.f}, a1 = a0, a2 = a0, a3 = a0;
            const int kb = ks * 32;
            #pragma unroll
            for (int kk = 0; kk < 32; kk++) {
                f32x4 xv = *(const f32x4*)&xbuf[(kb + kk) * 32 + (bt << 2)];
                a0 += w1[0][kk] * xv;
                a1 += w1[1][kk] * xv;
                a2 += w1[2][kk] * xv;
                a3 += w1[3][kk] * xv;
            }
            *(f32x4*)&part[ks * 512 + ((ct     ) * 8 + bt) * 4] = a0;
            *(f32x4*)&part[ks * 512 + ((ct +  4) * 8 + bt) * 4] = a1;
            *(f32x4*)&part[ks * 512 + ((ct +  8) * 8 + bt) * 4] = a2;
            *(f32x4*)&part[ks * 512 + ((ct + 12) * 8 + bt) * 4] = a3;
        }
        __syncthreads();

        // ---- P1 reduce stage 1 (16 -> 4 slices, vectorized) ----
        {
            const int out4 = tid & 127;
            const int qh   = tid >> 7;
            f32x4 s = {0.f,0.f,0.f,0.f};
            #pragma unroll
            for (int j = 0; j < 4; j++)
                s += *(const f32x4*)&part[(qh * 4 + j) * 512 + out4 * 4];
            *(f32x4*)&partR[qh * 512 + out4 * 4] = s;
        }
        __syncthreads();

        // ---- P1 reduce stage 2 + sigmoid; publish v, keep z & h local ----
        {
            float s = partR[rc * 32 + rb] + partR[512 + rc * 32 + rb]
                    + partR[1024 + rc * 32 + rb] + partR[1536 + rc * 32 + rb];
            float sig = 1.f / (1.f + __expf(-(ax1 + s)));
            if (rc < 8) {
                float hk = xbuf[(ch0 + rc) * 32 + rb];
                stg_coh(vT + (ch0 + rc) * 32 + rb, sig * hk);
            } else {
                zbuf[(rc - 8) * 33 + rb]  = sig;
                hsave[(rc - 8) * 33 + rb] = xbuf[(ch0 + rc - 8) * 32 + rb];
            }
        }
        flag_bar(flags, bid, bc); bc++;

        // ---- stage xbuf = v from vT (linear coalesced copy) ----
        {
            f32x4 ld[8];
            #pragma unroll
            for (int i = 0; i < 8; i++)
                ld[i] = ldg_coh_x4(vT + (tid + i * NTHR) * 4);
            asm volatile("s_waitcnt vmcnt(0)" ::: "memory");
            #pragma unroll
            for (int i = 0; i < 8; i++)
                *(f32x4*)&xbuf[(tid + i * NTHR) * 4] = ld[i];
        }
        __syncthreads();

        // ---- P2 dot: h_hat for 8 cols ----
        {
            f32x4 a0 = {0.f,0.f,0.f,0.f}, a1 = a0, a2 = a0, a3 = a0;
            const int kb = ks2 * 16;
            #pragma unroll
            for (int kk = 0; kk < 16; kk++) {
                f32x4 xv = *(const f32x4*)&xbuf[(kb + kk) * 32 + (bt2 << 2)];
                a0 += w2[0][kk] * xv;
                a1 += w2[1][kk] * xv;
                a2 += w2[2][kk] * xv;
                a3 += w2[3][kk] * xv;
            }
            const int cb = cth << 2;
            *(f32x4*)&part[ks2 * 256 + ((cb    ) * 8 + bt2) * 4] = a0;
            *(f32x4*)&part[ks2 * 256 + ((cb + 1) * 8 + bt2) * 4] = a1;
            *(f32x4*)&part[ks2 * 256 + ((cb + 2) * 8 + bt2) * 4] = a2;
            *(f32x4*)&part[ks2 * 256 + ((cb + 3) * 8 + bt2) * 4] = a3;
        }
        __syncthreads();

        // ---- P2 reduce stage 1 (32 -> 8 slices) ----
        {
            const int out4 = tid & 63;
            const int qh   = tid >> 6;
            f32x4 s = {0.f,0.f,0.f,0.f};
            #pragma unroll
            for (int j = 0; j < 4; j++)
                s += *(const f32x4*)&part[(qh * 4 + j) * 256 + out4 * 4];
            *(f32x4*)&partR[qh * 256 + out4 * 4] = s;
        }
        __syncthreads();

        // ---- P2 reduce stage 2 + tanh + blend; publish h ----
        if (tid < 256) {
            float s = 0.f;
            #pragma unroll
            for (int qh = 0; qh < 8; qh++) s += partR[qh * 256 + rc * 32 + rb];
            float pre = ax2 + s;
            float e2  = __expf(2.f * pre);
            float hh  = 1.f - 2.f / (e2 + 1.f);       // tanh
            float z   = zbuf[rc * 33 + rb];
            float h   = hsave[rc * 33 + rb];
            float hn  = (1.f - z) * h + z * hh;
            stg_coh(hxT + (ch0 + rc) * 32 + rb, hn);
            hnbuf[rc * 33 + rb] = hn;
            if (t == S_LEN - 1) hfin[rb * HID + ch0 + rc] = hn;
        }
        __syncthreads();
        // hseq for the GEMMs, coalesced 32B segments via LDS remap
        if (tid < 256) {
            const int c = tid & 7, b = tid >> 3;
            hseq[(size_t)((t << 5) + b) * HID + ch0 + c] = hnbuf[c * 33 + b];
        }
        flag_bar(flags, bid, bc); bc++;
    }
}

// ---------------------------------------------------------------------------
extern "C" void kernel_launch(void* const* d_in, const int* in_sizes, int n_in,
                              void* d_out, int out_size, void* d_ws, size_t ws_size,
                              hipStream_t stream)
{
    const int*   tokens = (const int*)  d_in[0];   // [S,B]
    const float* h0     = (const float*)d_in[1];   // [L,B,H]
    const float* emb    = (const float*)d_in[2];   // [V,H]
    const float* Wx     = (const float*)d_in[3];   // [L,3,H,H]
    const float* bx     = (const float*)d_in[4];   // [L,3,H]
    const float* U      = (const float*)d_in[5];   // [L,3,H,H]
    const float* Wy     = (const float*)d_in[6];   // [V,H]
    const float* by     = (const float*)d_in[7];   // [V]
    float*       out    = (float*)d_out;

    // workspace: axbuf [4096*1536]; hseq [4096*512]
    float* ws    = (float*)d_ws;
    float* axbuf = ws;
    float* hseq  = axbuf + (size_t)MROWS * 1536;

    const size_t logits_sz = (size_t)MROWS * VOCAB;
    float* hfin0 = out + logits_sz;
    float* hfin1 = out + logits_sz + BATCH * HID;

    // scratch carved from the logits region (overwritten by the final GEMM):
    //   vT [512x32], hxT [512x32], 2x64 barrier flags
    float*    vT    = out;                         // 16384 floats
    float*    hxT   = out + 16384;                 // 16384 floats
    unsigned* flags = (unsigned*)(out + 32768);
    hipMemsetAsync(flags, 0, 2 * NBLK * sizeof(unsigned), stream);

    // ax0 = emb[tokens] @ Wx[0] + bx[0]
    gemm_kernel<true, true><<<dim3(1536 / 64, MROWS / 64), 256, 0, stream>>>(
        emb, tokens, Wx, bx, axbuf, MROWS, 1536, HID);

    // layer-0 scan
    scan_coop_kernel<<<NBLK, NTHR, 0, stream>>>(
        axbuf, U, h0, hseq, hfin0, vT, hxT, flags);

    // ax1 = hseq @ Wx[1] + bx[1]
    gemm_kernel<false, true><<<dim3(1536 / 64, MROWS / 64), 256, 0, stream>>>(
        hseq, nullptr, Wx + 3 * HH, bx + 1536, axbuf, MROWS, 1536, HID);

    // layer-1 scan
    scan_coop_kernel<<<NBLK, NTHR, 0, stream>>>(
        axbuf, U + 3 * HH, h0 + BATCH * HID, hseq, hfin1, vT, hxT, flags + NBLK);

    // logits = tops @ Wy^T + by
    gemm_kernel<false, false><<<dim3((VOCAB + 63) / 64, MROWS / 64), 256, 0, stream>>>(
        hseq, nullptr, Wy, by, out, MROWS, VOCAB, HID);
}

// Round 4
// 4202.436 us; speedup vs baseline: 5.8985x; 5.8985x over previous
//
#include <hip/hip_runtime.h>
#include <cmath>

#define S_LEN 128
#define BATCH 32
#define HID   512
#define VOCAB 10000
#define MROWS (S_LEN * BATCH)   // 4096
#define HH    (HID * HID)

#define NBLK  64
#define NTHR  512

typedef float f32x4 __attribute__((ext_vector_type(4)));

// ---------------------------------------------------------------------------
// Tiled fp32 GEMM: C[M,N] = A[M,K] * B + bias[N]   (unchanged)
// ---------------------------------------------------------------------------
template<bool GATHER_A, bool B_KN>
__global__ __launch_bounds__(256) void gemm_kernel(
    const float* __restrict__ A, const int* __restrict__ tok,
    const float* __restrict__ Bmat, const float* __restrict__ bias,
    float* __restrict__ C, int M, int N, int K)
{
    __shared__ float As[32][68];
    __shared__ float Bs[32][68];
    __shared__ int   toks[64];

    const int tid = threadIdx.x;
    const int m0  = blockIdx.y * 64;
    const int n0  = blockIdx.x * 64;

    if (GATHER_A && tid < 64) toks[tid] = tok[m0 + tid];
    __syncthreads();

    const int tx = tid & 15;
    const int ty = tid >> 4;
    const int lr = tid >> 3;
    const int lc = (tid & 7) * 4;

    float acc[4][4] = {};

    for (int k0 = 0; k0 < K; k0 += 32) {
        #pragma unroll
        for (int rep = 0; rep < 2; rep++) {
            int r = lr + rep * 32;
            const float* arow;
            if (GATHER_A) arow = A + (size_t)toks[r] * K;
            else          arow = A + (size_t)(m0 + r) * K;
            float4 v = *(const float4*)(arow + k0 + lc);
            As[lc + 0][r] = v.x; As[lc + 1][r] = v.y;
            As[lc + 2][r] = v.z; As[lc + 3][r] = v.w;
        }
        if (B_KN) {
            int g    = n0 >> 9;
            int col0 = n0 & 511;
            const float* bbase = Bmat + (size_t)g * K * 512 + col0;
            int bc = (tid & 15) * 4;
            int bk = tid >> 4;
            #pragma unroll
            for (int rep = 0; rep < 2; rep++) {
                int kk = bk + rep * 16;
                float4 v = *(const float4*)(bbase + (size_t)(k0 + kk) * 512 + bc);
                *(float4*)&Bs[kk][bc] = v;
            }
        } else {
            #pragma unroll
            for (int rep = 0; rep < 2; rep++) {
                int r = lr + rep * 32;
                int n = n0 + r;
                float4 v = make_float4(0.f, 0.f, 0.f, 0.f);
                if (n < N) v = *(const float4*)(Bmat + (size_t)n * K + k0 + lc);
                Bs[lc + 0][r] = v.x; Bs[lc + 1][r] = v.y;
                Bs[lc + 2][r] = v.z; Bs[lc + 3][r] = v.w;
            }
        }
        __syncthreads();
        #pragma unroll
        for (int k = 0; k < 32; k++) {
            float4 a4 = *(const float4*)&As[k][ty * 4];
            float4 b4 = *(const float4*)&Bs[k][tx * 4];
            float av[4] = {a4.x, a4.y, a4.z, a4.w};
            float bv[4] = {b4.x, b4.y, b4.z, b4.w};
            #pragma unroll
            for (int i = 0; i < 4; i++)
                #pragma unroll
                for (int j = 0; j < 4; j++)
                    acc[i][j] = fmaf(av[i], bv[j], acc[i][j]);
        }
        __syncthreads();
    }
    #pragma unroll
    for (int i = 0; i < 4; i++) {
        int m = m0 + ty * 4 + i;
        #pragma unroll
        for (int j = 0; j < 4; j++) {
            int n = n0 + tx * 4 + j;
            if (n < N) C[(size_t)m * N + n] = acc[i][j] + bias[n];
        }
    }
}

// ---------------------------------------------------------------------------
// Agent-coherent (LLC-direct) access: sc1 bypasses the per-XCD L2.
// Caller must s_waitcnt vmcnt(0) before consuming ldg_coh_x4 results.
// ---------------------------------------------------------------------------
__device__ __forceinline__ f32x4 ldg_coh_x4(const float* p) {
    f32x4 r;
    asm volatile("global_load_dwordx4 %0, %1, off sc1"
                 : "=v"(r) : "v"(p) : "memory");
    return r;
}
__device__ __forceinline__ void stg_coh(float* p, float v) {
    asm volatile("global_store_dword %0, %1, off sc1"
                 :: "v"(p), "v"(v) : "memory");
}

// ---------------------------------------------------------------------------
// Contention-free device barrier: per-block monotonic flags, 64-lane poll.
// ---------------------------------------------------------------------------
__device__ __forceinline__ void flag_bar(unsigned* flags, int bid, unsigned target)
{
    asm volatile("s_waitcnt vmcnt(0)" ::: "memory");
    __syncthreads();
    if (threadIdx.x == 0)
        __hip_atomic_store(&flags[bid], target, __ATOMIC_RELEASE, __HIP_MEMORY_SCOPE_AGENT);
    if (threadIdx.x < NBLK) {
        while (__hip_atomic_load(&flags[threadIdx.x], __ATOMIC_RELAXED,
                                 __HIP_MEMORY_SCOPE_AGENT) < target)
            __builtin_amdgcn_s_sleep(1);
    }
    __syncthreads();
}

// ---------------------------------------------------------------------------
// Cooperative column-split GRU layer scan, v4.
//   - Weights in LDS (v3's VGPR-weights spilled to scratch: 5.3 GB fetch).
//   - b-fast exchange (vT/hxT[512][32]) + [k][b] xbuf: linear coalesced
//     staging, conflict-free dot reads (kept from v3).
//   - Block owns 8 h-cols: computes r AND z for them; only v=r*h and h
//     cross blocks (64 KB each per step).
// Layouts:
//   Wrz[k][c]   512x16 (c: 0-7 = r-gate cols ch0.., 8-15 = z-gate)
//   Whh[k][c]   512x8, 16B-chunk XOR swizzle (chunk ^= (k>>4)&1) to break
//               the k-slice-16-apart same-bank aliasing
//   xbuf[k][b]  512x32
//   P1 dot: 4ct x 8bt x 16ks (K=32/thread), acc = 4 cols x 4-batch-vec
//   P2 dot: 2ct x 8bt x 32ks (K=16/thread)
// ---------------------------------------------------------------------------
__global__ __launch_bounds__(NTHR) void scan_coop_kernel(
    const float* __restrict__ ax, const float* __restrict__ Ul,
    const float* __restrict__ h0g, float* __restrict__ hseq,
    float* __restrict__ hfin, float* __restrict__ vT,
    float* __restrict__ hxT, unsigned* __restrict__ flags)
{
    __shared__ float Wrz[512 * 16];    // 32 KB
    __shared__ float Whh[512 * 8];     // 16 KB
    __shared__ float xbuf[512 * 32];   // 64 KB
    __shared__ float part[16 * 512];   // 32 KB (P1: 16x[16c x 32b]; P2: 32x[8c x 32b]; also hn scratch)
    __shared__ float partR[2048];      //  8 KB (P1: 4x512; P2: 8x256)
    __shared__ float zbuf[8 * 33];
    __shared__ float hsave[8 * 33];

    const int tid = threadIdx.x;
    const int bid = blockIdx.x;
    const int ch0 = bid << 3;          // owned h-column base (8 cols)

    // P1 dot mapping
    const int bt  = tid & 7;           // b0 = bt*4
    const int ct  = (tid >> 3) & 3;    // c0 = ct*4
    const int ks  = tid >> 5;          // 0..15, kb = ks*32
    // P2 dot mapping
    const int ct2 = (tid >> 3) & 1;    // c0 = ct2*4
    const int ks2 = tid >> 4;          // 0..31, kb = ks2*16
    // reduce / scalar mapping
    const int rb  = tid & 31;
    const int rc  = tid >> 5;          // 0..15

    // ---- one-time: weights into LDS ----
    for (int idx = tid; idx < 512 * 16; idx += NTHR) {
        int c = idx & 15, k = idx >> 4;
        Wrz[k * 16 + c] = Ul[(size_t)(c >> 3) * HH + (size_t)k * HID + ch0 + (c & 7)];
    }
    for (int idx = tid; idx < 512 * 8; idx += NTHR) {
        int c = idx & 7, k = idx >> 3;
        int cs = (((c >> 2) ^ ((k >> 4) & 1)) << 2) | (c & 3);   // chunk XOR swizzle
        Whh[k * 8 + cs] = Ul[(size_t)2 * HH + (size_t)k * HID + ch0 + c];
    }

    // ---- prefill hxT with h0 (own 8 rows), then global barrier ----
    if (tid < 256) {
        int c = tid >> 5, b = tid & 31;
        stg_coh(hxT + (ch0 + c) * 32 + b, h0g[b * HID + ch0 + c]);
    }
    unsigned bc = 1;
    flag_bar(flags, bid, bc); bc++;

    for (int t = 0; t < S_LEN; t++) {
        // ---- prefetch ax terms (normal loads, L2-cached) ----
        const size_t axrow = (size_t)((t << 5) + rb) * 1536;
        const float ax1 = ax[axrow + (rc < 8 ? ch0 + rc : 512 + ch0 + (rc - 8))];
        const float ax2 = (tid < 256) ? ax[axrow + 1024 + ch0 + (tid >> 5)] : 0.f;

        // ---- stage xbuf = h(t-1) from hxT (linear coalesced copy) ----
        {
            f32x4 ld[8];
            #pragma unroll
            for (int i = 0; i < 8; i++)
                ld[i] = ldg_coh_x4(hxT + (size_t)(tid + i * NTHR) * 4);
            asm volatile("s_waitcnt vmcnt(0)" ::: "memory");
            #pragma unroll
            for (int i = 0; i < 8; i++)
                *(f32x4*)&xbuf[(tid + i * NTHR) * 4] = ld[i];
        }
        __syncthreads();

        // ---- P1 dot: r,z for 16 cols; per k: 1 w-b128 + 1 x-b128, 16 FMA ----
        {
            f32x4 a0 = {0.f,0.f,0.f,0.f}, a1 = a0, a2 = a0, a3 = a0;
            const int kb = ks << 5;
            #pragma unroll
            for (int kk = 0; kk < 32; kk++) {
                int k = kb + kk;
                f32x4 wv = *(const f32x4*)&Wrz[(k << 4) + (ct << 2)];
                f32x4 xv = *(const f32x4*)&xbuf[(k << 5) + (bt << 2)];
                a0 += wv.x * xv;
                a1 += wv.y * xv;
                a2 += wv.z * xv;
                a3 += wv.w * xv;
            }
            const int c0 = ct << 2;
            *(f32x4*)&part[(ks << 9) + ((c0    ) << 5) + (bt << 2)] = a0;
            *(f32x4*)&part[(ks << 9) + ((c0 + 1) << 5) + (bt << 2)] = a1;
            *(f32x4*)&part[(ks << 9) + ((c0 + 2) << 5) + (bt << 2)] = a2;
            *(f32x4*)&part[(ks << 9) + ((c0 + 3) << 5) + (bt << 2)] = a3;
        }
        __syncthreads();

        // ---- P1 reduce stage 1 (16 -> 4 slices, vectorized) ----
        {
            const int out4 = tid & 127;
            const int qh   = tid >> 7;
            f32x4 s = {0.f,0.f,0.f,0.f};
            #pragma unroll
            for (int j = 0; j < 4; j++)
                s += *(const f32x4*)&part[((qh << 2) + j) * 512 + (out4 << 2)];
            *(f32x4*)&partR[(qh << 9) + (out4 << 2)] = s;
        }
        __syncthreads();

        // ---- P1 reduce stage 2 + sigmoid; publish v, keep z & h local ----
        {
            float s = partR[(rc << 5) + rb] + partR[512 + (rc << 5) + rb]
                    + partR[1024 + (rc << 5) + rb] + partR[1536 + (rc << 5) + rb];
            float sig = 1.f / (1.f + __expf(-(ax1 + s)));
            if (rc < 8) {
                float hk = xbuf[((ch0 + rc) << 5) + rb];
                stg_coh(vT + (ch0 + rc) * 32 + rb, sig * hk);
            } else {
                zbuf[(rc - 8) * 33 + rb]  = sig;
                hsave[(rc - 8) * 33 + rb] = xbuf[((ch0 + rc - 8) << 5) + rb];
            }
        }
        flag_bar(flags, bid, bc); bc++;

        // ---- stage xbuf = v from vT (linear coalesced copy) ----
        {
            f32x4 ld[8];
            #pragma unroll
            for (int i = 0; i < 8; i++)
                ld[i] = ldg_coh_x4(vT + (size_t)(tid + i * NTHR) * 4);
            asm volatile("s_waitcnt vmcnt(0)" ::: "memory");
            #pragma unroll
            for (int i = 0; i < 8; i++)
                *(f32x4*)&xbuf[(tid + i * NTHR) * 4] = ld[i];
        }
        __syncthreads();

        // ---- P2 dot: h_hat for 8 cols ----
        {
            f32x4 a0 = {0.f,0.f,0.f,0.f}, a1 = a0, a2 = a0, a3 = a0;
            const int kb = ks2 << 4;
            #pragma unroll
            for (int kk = 0; kk < 16; kk++) {
                int k = kb + kk;
                int wch = ((ct2 ^ ((k >> 4) & 1)) << 2);     // swizzled chunk
                f32x4 wv = *(const f32x4*)&Whh[(k << 3) + wch];
                f32x4 xv = *(const f32x4*)&xbuf[(k << 5) + (bt << 2)];
                a0 += wv.x * xv;
                a1 += wv.y * xv;
                a2 += wv.z * xv;
                a3 += wv.w * xv;
            }
            const int c0 = ct2 << 2;
            *(f32x4*)&part[(ks2 << 8) + ((c0    ) << 5) + (bt << 2)] = a0;
            *(f32x4*)&part[(ks2 << 8) + ((c0 + 1) << 5) + (bt << 2)] = a1;
            *(f32x4*)&part[(ks2 << 8) + ((c0 + 2) << 5) + (bt << 2)] = a2;
            *(f32x4*)&part[(ks2 << 8) + ((c0 + 3) << 5) + (bt << 2)] = a3;
        }
        __syncthreads();

        // ---- P2 reduce stage 1 (32 -> 8 slices) ----
        {
            const int out4 = tid & 63;
            const int qh   = tid >> 6;
            f32x4 s = {0.f,0.f,0.f,0.f};
            #pragma unroll
            for (int j = 0; j < 4; j++)
                s += *(const f32x4*)&part[((qh << 2) + j) * 256 + (out4 << 2)];
            *(f32x4*)&partR[(qh << 8) + (out4 << 2)] = s;
        }
        __syncthreads();

        // ---- P2 reduce stage 2 + tanh + blend; publish h ----
        if (tid < 256) {
            const int c = tid >> 5, b = tid & 31;
            float s = 0.f;
            #pragma unroll
            for (int qh = 0; qh < 8; qh++) s += partR[(qh << 8) + (c << 5) + b];
            float pre = ax2 + s;
            float e2  = __expf(2.f * pre);
            float hh  = 1.f - 2.f / (e2 + 1.f);       // tanh
            float z   = zbuf[c * 33 + b];
            float h   = hsave[c * 33 + b];
            float hn  = (1.f - z) * h + z * hh;
            stg_coh(hxT + (ch0 + c) * 32 + b, hn);
            part[c * 33 + b] = hn;                    // part free here; hn scratch
            if (t == S_LEN - 1) hfin[b * HID + ch0 + c] = hn;
        }
        __syncthreads();
        // hseq for the GEMMs, coalesced 32B segments
        if (tid < 256) {
            const int c = tid & 7, b = tid >> 3;
            hseq[(size_t)((t << 5) + b) * HID + ch0 + c] = part[c * 33 + b];
        }
        flag_bar(flags, bid, bc); bc++;
    }
}

// ---------------------------------------------------------------------------
extern "C" void kernel_launch(void* const* d_in, const int* in_sizes, int n_in,
                              void* d_out, int out_size, void* d_ws, size_t ws_size,
                              hipStream_t stream)
{
    const int*   tokens = (const int*)  d_in[0];   // [S,B]
    const float* h0     = (const float*)d_in[1];   // [L,B,H]
    const float* emb    = (const float*)d_in[2];   // [V,H]
    const float* Wx     = (const float*)d_in[3];   // [L,3,H,H]
    const float* bx     = (const float*)d_in[4];   // [L,3,H]
    const float* U      = (const float*)d_in[5];   // [L,3,H,H]
    const float* Wy     = (const float*)d_in[6];   // [V,H]
    const float* by     = (const float*)d_in[7];   // [V]
    float*       out    = (float*)d_out;

    // workspace: axbuf [4096*1536]; hseq [4096*512]
    float* ws    = (float*)d_ws;
    float* axbuf = ws;
    float* hseq  = axbuf + (size_t)MROWS * 1536;

    const size_t logits_sz = (size_t)MROWS * VOCAB;
    float* hfin0 = out + logits_sz;
    float* hfin1 = out + logits_sz + BATCH * HID;

    // scratch carved from the logits region (overwritten by the final GEMM):
    //   vT [512x32], hxT [512x32], 2x64 barrier flags
    float*    vT    = out;                         // 16384 floats
    float*    hxT   = out + 16384;                 // 16384 floats
    unsigned* flags = (unsigned*)(out + 32768);
    hipMemsetAsync(flags, 0, 2 * NBLK * sizeof(unsigned), stream);

    // ax0 = emb[tokens] @ Wx[0] + bx[0]
    gemm_kernel<true, true><<<dim3(1536 / 64, MROWS / 64), 256, 0, stream>>>(
        emb, tokens, Wx, bx, axbuf, MROWS, 1536, HID);

    // layer-0 scan
    scan_coop_kernel<<<NBLK, NTHR, 0, stream>>>(
        axbuf, U, h0, hseq, hfin0, vT, hxT, flags);

    // ax1 = hseq @ Wx[1] + bx[1]
    gemm_kernel<false, true><<<dim3(1536 / 64, MROWS / 64), 256, 0, stream>>>(
        hseq, nullptr, Wx + 3 * HH, bx + 1536, axbuf, MROWS, 1536, HID);

    // layer-1 scan
    scan_coop_kernel<<<NBLK, NTHR, 0, stream>>>(
        axbuf, U + 3 * HH, h0 + BATCH * HID, hseq, hfin1, vT, hxT, flags + NBLK);

    // logits = tops @ Wy^T + by
    gemm_kernel<false, false><<<dim3((VOCAB + 63) / 64, MROWS / 64), 256, 0, stream>>>(
        hseq, nullptr, Wy, by, out, MROWS, VOCAB, HID);
}

// Round 5
// 3453.473 us; speedup vs baseline: 7.1778x; 1.2169x over previous
//
#include <hip/hip_runtime.h>
#include <cmath>

#define S_LEN 128
#define BATCH 32
#define HID   512
#define VOCAB 10000
#define MROWS (S_LEN * BATCH)   // 4096
#define HH    (HID * HID)

#define NBLK  64
#define NTHR  512

typedef float f32x4 __attribute__((ext_vector_type(4)));

// ---------------------------------------------------------------------------
// Tiled fp32 GEMM (64x64 tile): C = A * B + bias
//   C_T: write C transposed as C[n*M + m] (axT layout for the scan)
// ---------------------------------------------------------------------------
template<bool GATHER_A, bool B_KN, bool C_T>
__global__ __launch_bounds__(256) void gemm_kernel(
    const float* __restrict__ A, const int* __restrict__ tok,
    const float* __restrict__ Bmat, const float* __restrict__ bias,
    float* __restrict__ C, int M, int N, int K)
{
    __shared__ float As[32][68];
    __shared__ float Bs[32][68];
    __shared__ int   toks[64];

    const int tid = threadIdx.x;
    const int m0  = blockIdx.y * 64;
    const int n0  = blockIdx.x * 64;

    if (GATHER_A && tid < 64) toks[tid] = tok[m0 + tid];
    __syncthreads();

    const int tx = tid & 15;
    const int ty = tid >> 4;
    const int lr = tid >> 3;
    const int lc = (tid & 7) * 4;

    float acc[4][4] = {};

    for (int k0 = 0; k0 < K; k0 += 32) {
        #pragma unroll
        for (int rep = 0; rep < 2; rep++) {
            int r = lr + rep * 32;
            const float* arow;
            if (GATHER_A) arow = A + (size_t)toks[r] * K;
            else          arow = A + (size_t)(m0 + r) * K;
            float4 v = *(const float4*)(arow + k0 + lc);
            As[lc + 0][r] = v.x; As[lc + 1][r] = v.y;
            As[lc + 2][r] = v.z; As[lc + 3][r] = v.w;
        }
        if (B_KN) {
            int g    = n0 >> 9;
            int col0 = n0 & 511;
            const float* bbase = Bmat + (size_t)g * K * 512 + col0;
            int bc = (tid & 15) * 4;
            int bk = tid >> 4;
            #pragma unroll
            for (int rep = 0; rep < 2; rep++) {
                int kk = bk + rep * 16;
                float4 v = *(const float4*)(bbase + (size_t)(k0 + kk) * 512 + bc);
                *(float4*)&Bs[kk][bc] = v;
            }
        } else {
            #pragma unroll
            for (int rep = 0; rep < 2; rep++) {
                int r = lr + rep * 32;
                int n = n0 + r;
                float4 v = make_float4(0.f, 0.f, 0.f, 0.f);
                if (n < N) v = *(const float4*)(Bmat + (size_t)n * K + k0 + lc);
                Bs[lc + 0][r] = v.x; Bs[lc + 1][r] = v.y;
                Bs[lc + 2][r] = v.z; Bs[lc + 3][r] = v.w;
            }
        }
        __syncthreads();
        #pragma unroll
        for (int k = 0; k < 32; k++) {
            float4 a4 = *(const float4*)&As[k][ty * 4];
            float4 b4 = *(const float4*)&Bs[k][tx * 4];
            float av[4] = {a4.x, a4.y, a4.z, a4.w};
            float bv[4] = {b4.x, b4.y, b4.z, b4.w};
            #pragma unroll
            for (int i = 0; i < 4; i++)
                #pragma unroll
                for (int j = 0; j < 4; j++)
                    acc[i][j] = fmaf(av[i], bv[j], acc[i][j]);
        }
        __syncthreads();
    }
    if (C_T) {
        #pragma unroll
        for (int j = 0; j < 4; j++) {
            int n = n0 + tx * 4 + j;
            float bn = bias[n];
            float4 v = make_float4(acc[0][j] + bn, acc[1][j] + bn,
                                   acc[2][j] + bn, acc[3][j] + bn);
            *(float4*)&C[(size_t)n * M + m0 + ty * 4] = v;
        }
    } else {
        #pragma unroll
        for (int i = 0; i < 4; i++) {
            int m = m0 + ty * 4 + i;
            #pragma unroll
            for (int j = 0; j < 4; j++) {
                int n = n0 + tx * 4 + j;
                if (n < N) C[(size_t)m * N + n] = acc[i][j] + bias[n];
            }
        }
    }
}

// ---------------------------------------------------------------------------
// 128x128-tile fp32 GEMM for the logits (B row-major [N][K]).
// 256 threads, 8x8 microtile: 64 FMA per 4 LDS b128 reads -> VALU-bound.
// ---------------------------------------------------------------------------
__global__ __launch_bounds__(256) void gemm128_kernel(
    const float* __restrict__ A, const float* __restrict__ B,
    const float* __restrict__ bias, float* __restrict__ C,
    int M, int N, int K)
{
    __shared__ float As[16][132];
    __shared__ float Bs[16][132];

    const int tid = threadIdx.x;
    const int m0  = blockIdx.y * 128;
    const int n0  = blockIdx.x * 128;
    const int tx  = tid & 15;
    const int ty  = tid >> 4;
    const int lr  = tid >> 2;          // 0..63
    const int lc  = (tid & 3) * 4;     // 0..12

    float acc[8][8] = {};

    for (int k0 = 0; k0 < K; k0 += 16) {
        #pragma unroll
        for (int rep = 0; rep < 2; rep++) {
            int r = lr + rep * 64;
            float4 va = *(const float4*)(A + (size_t)(m0 + r) * K + k0 + lc);
            As[lc + 0][r] = va.x; As[lc + 1][r] = va.y;
            As[lc + 2][r] = va.z; As[lc + 3][r] = va.w;
            int n = n0 + r;
            float4 vb = make_float4(0.f, 0.f, 0.f, 0.f);
            if (n < N) vb = *(const float4*)(B + (size_t)n * K + k0 + lc);
            Bs[lc + 0][r] = vb.x; Bs[lc + 1][r] = vb.y;
            Bs[lc + 2][r] = vb.z; Bs[lc + 3][r] = vb.w;
        }
        __syncthreads();
        #pragma unroll
        for (int k = 0; k < 16; k++) {
            f32x4 a0 = *(const f32x4*)&As[k][ty * 8];
            f32x4 a1 = *(const f32x4*)&As[k][ty * 8 + 4];
            f32x4 b0 = *(const f32x4*)&Bs[k][tx * 8];
            f32x4 b1 = *(const f32x4*)&Bs[k][tx * 8 + 4];
            float av[8] = {a0.x,a0.y,a0.z,a0.w,a1.x,a1.y,a1.z,a1.w};
            float bv[8] = {b0.x,b0.y,b0.z,b0.w,b1.x,b1.y,b1.z,b1.w};
            #pragma unroll
            for (int i = 0; i < 8; i++)
                #pragma unroll
                for (int j = 0; j < 8; j++)
                    acc[i][j] = fmaf(av[i], bv[j], acc[i][j]);
        }
        __syncthreads();
    }
    const bool full = (n0 + 128 <= N);
    #pragma unroll
    for (int i = 0; i < 8; i++) {
        int m = m0 + ty * 8 + i;
        if (full) {
            int n = n0 + tx * 8;
            float4 v0 = make_float4(acc[i][0]+bias[n+0], acc[i][1]+bias[n+1],
                                    acc[i][2]+bias[n+2], acc[i][3]+bias[n+3]);
            float4 v1 = make_float4(acc[i][4]+bias[n+4], acc[i][5]+bias[n+5],
                                    acc[i][6]+bias[n+6], acc[i][7]+bias[n+7]);
            *(float4*)&C[(size_t)m * N + n]     = v0;
            *(float4*)&C[(size_t)m * N + n + 4] = v1;
        } else {
            #pragma unroll
            for (int j = 0; j < 8; j++) {
                int n = n0 + tx * 8 + j;
                if (n < N) C[(size_t)m * N + n] = acc[i][j] + bias[n];
            }
        }
    }
}

// ---------------------------------------------------------------------------
// Agent-coherent (LLC-direct) access: sc1 bypasses the per-XCD L2.
// ---------------------------------------------------------------------------
__device__ __forceinline__ f32x4 ldg_coh_x4(const float* p) {
    f32x4 r;
    asm volatile("global_load_dwordx4 %0, %1, off sc1"
                 : "=v"(r) : "v"(p) : "memory");
    return r;
}
__device__ __forceinline__ void stg_coh(float* p, float v) {
    asm volatile("global_store_dword %0, %1, off sc1"
                 :: "v"(p), "v"(v) : "memory");
}

// ---------------------------------------------------------------------------
// Split-phase contention-free device barrier (per-block monotonic flags).
// arrive(): drain own stores, block-sync, publish flag.  wait(): poll+sync.
// Useful work can be placed between arrive and wait.
// ---------------------------------------------------------------------------
__device__ __forceinline__ void bar_arrive(unsigned* flags, int bid, unsigned target)
{
    asm volatile("s_waitcnt vmcnt(0)" ::: "memory");
    __syncthreads();
    if (threadIdx.x == 0)
        __hip_atomic_store(&flags[bid], target, __ATOMIC_RELEASE, __HIP_MEMORY_SCOPE_AGENT);
}
__device__ __forceinline__ void bar_wait(unsigned* flags, unsigned target)
{
    if (threadIdx.x < NBLK) {
        while (__hip_atomic_load(&flags[threadIdx.x], __ATOMIC_RELAXED,
                                 __HIP_MEMORY_SCOPE_AGENT) < target)
            __builtin_amdgcn_s_sleep(1);
    }
    __syncthreads();
}

// ---------------------------------------------------------------------------
// Cooperative column-split GRU layer scan, v5.
//   - r/z gate dots split: z dot runs INSIDE the v-barrier window; hseq
//     write + next-step ax prefetch run inside the h-barrier window.
//   - ax consumed from axT[1536][4096] ((t,b)-fast): coalesced reads.
//   - weights in LDS, chunk-XOR swizzled (chunk ^= ks&1) for 2-way-max
//     conflicts on the w-read; xbuf [k][b] with linear staging.
// All three dots use the same mapping: bt=tid&7 (4 b), ct1=(tid>>3)&1 (4 c),
// ks=tid>>4 (0..31, K=16).  part = 32 slices x [8c x 32b].
// ---------------------------------------------------------------------------
__global__ __launch_bounds__(NTHR) void scan_coop_kernel(
    const float* __restrict__ axT, const float* __restrict__ Ul,
    const float* __restrict__ h0g, float* __restrict__ hseq,
    float* __restrict__ hfin, float* __restrict__ vT,
    float* __restrict__ hxT, unsigned* __restrict__ flags)
{
    __shared__ float Wr[512 * 8];      // 16 KB
    __shared__ float Wz[512 * 8];      // 16 KB
    __shared__ float Wh[512 * 8];      // 16 KB
    __shared__ float xbuf[512 * 32];   // 64 KB  [k][b]
    __shared__ float part[32 * 256];   // 32 KB
    __shared__ float partR[8 * 256];   //  8 KB
    __shared__ float zbuf[8 * 33];
    __shared__ float hsave[8 * 33];
    __shared__ float hnb[8 * 33];

    const int tid = threadIdx.x;
    const int bid = blockIdx.x;
    const int ch0 = bid << 3;          // owned 8 hidden columns

    const int bt  = tid & 7;           // b0 = bt*4
    const int ct1 = (tid >> 3) & 1;    // c0 = ct1*4
    const int ks  = tid >> 4;          // 0..31, kb = ks*16
    const int wsel = ((ct1 ^ ks) & 1) << 2;   // swizzled w-chunk
    const int rc  = tid >> 5;          // reduce col (0..15; use <8)
    const int rb  = tid & 31;          // reduce batch

    // ---- one-time: weights into LDS (chunk-XOR swizzle by k>>4) ----
    for (int idx = tid; idx < 512 * 8; idx += NTHR) {
        int c = idx & 7, k = idx >> 3;
        int p = (k << 3) + ((((c >> 2) ^ (k >> 4)) & 1) << 2) + (c & 3);
        Wr[p] = Ul[                (size_t)k * HID + ch0 + c];
        Wz[p] = Ul[(size_t)1 * HH + (size_t)k * HID + ch0 + c];
        Wh[p] = Ul[(size_t)2 * HH + (size_t)k * HID + ch0 + c];
    }

    // ---- prefill hxT with h0 (own 8 rows) ----
    if (tid < 256)
        stg_coh(hxT + (ch0 + rc) * 32 + rb, h0g[rb * HID + ch0 + rc]);
    unsigned bc = 1;
    bar_arrive(flags, bid, bc);

    // ---- ax prefetch for t=0 (coalesced from axT) ----
    float axr = 0.f, axz = 0.f, axh = 0.f;
    if (tid < 256) {
        axr = axT[(size_t)(       ch0 + rc) * MROWS + rb];
        axz = axT[(size_t)( 512 + ch0 + rc) * MROWS + rb];
        axh = axT[(size_t)(1024 + ch0 + rc) * MROWS + rb];
    }
    bar_wait(flags, bc); bc++;

    for (int t = 0; t < S_LEN; t++) {
        // ---- stage xbuf = h(t-1) from hxT (linear coalesced copy) ----
        {
            f32x4 ld[8];
            #pragma unroll
            for (int i = 0; i < 8; i++)
                ld[i] = ldg_coh_x4(hxT + (size_t)(tid + i * NTHR) * 4);
            asm volatile("s_waitcnt vmcnt(0)" ::: "memory");
            #pragma unroll
            for (int i = 0; i < 8; i++)
                *(f32x4*)&xbuf[(tid + i * NTHR) * 4] = ld[i];
        }
        __syncthreads();

        // ---- P1r dot (8 r-cols) ----
        {
            f32x4 a0 = {0.f,0.f,0.f,0.f}, a1 = a0, a2 = a0, a3 = a0;
            const int kb = ks << 4;
            #pragma unroll
            for (int kk = 0; kk < 16; kk++) {
                int k = kb + kk;
                f32x4 wv = *(const f32x4*)&Wr[(k << 3) + wsel];
                f32x4 xv = *(const f32x4*)&xbuf[(k << 5) + (bt << 2)];
                a0 += wv.x * xv; a1 += wv.y * xv;
                a2 += wv.z * xv; a3 += wv.w * xv;
            }
            const int c0 = ct1 << 2;
            *(f32x4*)&part[(ks << 8) + ((c0    ) << 5) + (bt << 2)] = a0;
            *(f32x4*)&part[(ks << 8) + ((c0 + 1) << 5) + (bt << 2)] = a1;
            *(f32x4*)&part[(ks << 8) + ((c0 + 2) << 5) + (bt << 2)] = a2;
            *(f32x4*)&part[(ks << 8) + ((c0 + 3) << 5) + (bt << 2)] = a3;
        }
        __syncthreads();
        // ---- r reduce stage 1 (32 -> 8 slices) ----
        {
            const int out4 = tid & 63, qh = tid >> 6;
            f32x4 s = {0.f,0.f,0.f,0.f};
            #pragma unroll
            for (int j = 0; j < 4; j++)
                s += *(const f32x4*)&part[(((qh << 2) + j) << 8) + (out4 << 2)];
            *(f32x4*)&partR[(qh << 8) + (out4 << 2)] = s;
        }
        __syncthreads();
        // ---- r reduce stage 2 + sigmoid; publish v = r*h ----
        if (tid < 256) {
            float s = 0.f;
            #pragma unroll
            for (int qh = 0; qh < 8; qh++) s += partR[(qh << 8) + (rc << 5) + rb];
            float sig = 1.f / (1.f + __expf(-(axr + s)));
            float hk  = xbuf[((ch0 + rc) << 5) + rb];
            stg_coh(vT + (ch0 + rc) * 32 + rb, sig * hk);
        }
        bar_arrive(flags, bid, bc);

        // ================= inside v-barrier window: z gate =================
        {
            f32x4 a0 = {0.f,0.f,0.f,0.f}, a1 = a0, a2 = a0, a3 = a0;
            const int kb = ks << 4;
            #pragma unroll
            for (int kk = 0; kk < 16; kk++) {
                int k = kb + kk;
                f32x4 wv = *(const f32x4*)&Wz[(k << 3) + wsel];
                f32x4 xv = *(const f32x4*)&xbuf[(k << 5) + (bt << 2)];
                a0 += wv.x * xv; a1 += wv.y * xv;
                a2 += wv.z * xv; a3 += wv.w * xv;
            }
            const int c0 = ct1 << 2;
            *(f32x4*)&part[(ks << 8) + ((c0    ) << 5) + (bt << 2)] = a0;
            *(f32x4*)&part[(ks << 8) + ((c0 + 1) << 5) + (bt << 2)] = a1;
            *(f32x4*)&part[(ks << 8) + ((c0 + 2) << 5) + (bt << 2)] = a2;
            *(f32x4*)&part[(ks << 8) + ((c0 + 3) << 5) + (bt << 2)] = a3;
        }
        __syncthreads();
        {
            const int out4 = tid & 63, qh = tid >> 6;
            f32x4 s = {0.f,0.f,0.f,0.f};
            #pragma unroll
            for (int j = 0; j < 4; j++)
                s += *(const f32x4*)&part[(((qh << 2) + j) << 8) + (out4 << 2)];
            *(f32x4*)&partR[(qh << 8) + (out4 << 2)] = s;
        }
        __syncthreads();
        if (tid < 256) {
            float s = 0.f;
            #pragma unroll
            for (int qh = 0; qh < 8; qh++) s += partR[(qh << 8) + (rc << 5) + rb];
            zbuf[rc * 33 + rb]  = 1.f / (1.f + __expf(-(axz + s)));
            hsave[rc * 33 + rb] = xbuf[((ch0 + rc) << 5) + rb];
        }
        // ===================================================================
        bar_wait(flags, bc); bc++;

        // ---- stage xbuf = v from vT ----
        {
            f32x4 ld[8];
            #pragma unroll
            for (int i = 0; i < 8; i++)
                ld[i] = ldg_coh_x4(vT + (size_t)(tid + i * NTHR) * 4);
            asm volatile("s_waitcnt vmcnt(0)" ::: "memory");
            #pragma unroll
            for (int i = 0; i < 8; i++)
                *(f32x4*)&xbuf[(tid + i * NTHR) * 4] = ld[i];
        }
        __syncthreads();

        // ---- P2 dot (8 h_hat cols) ----
        {
            f32x4 a0 = {0.f,0.f,0.f,0.f}, a1 = a0, a2 = a0, a3 = a0;
            const int kb = ks << 4;
            #pragma unroll
            for (int kk = 0; kk < 16; kk++) {
                int k = kb + kk;
                f32x4 wv = *(const f32x4*)&Wh[(k << 3) + wsel];
                f32x4 xv = *(const f32x4*)&xbuf[(k << 5) + (bt << 2)];
                a0 += wv.x * xv; a1 += wv.y * xv;
                a2 += wv.z * xv; a3 += wv.w * xv;
            }
            const int c0 = ct1 << 2;
            *(f32x4*)&part[(ks << 8) + ((c0    ) << 5) + (bt << 2)] = a0;
            *(f32x4*)&part[(ks << 8) + ((c0 + 1) << 5) + (bt << 2)] = a1;
            *(f32x4*)&part[(ks << 8) + ((c0 + 2) << 5) + (bt << 2)] = a2;
            *(f32x4*)&part[(ks << 8) + ((c0 + 3) << 5) + (bt << 2)] = a3;
        }
        __syncthreads();
        {
            const int out4 = tid & 63, qh = tid >> 6;
            f32x4 s = {0.f,0.f,0.f,0.f};
            #pragma unroll
            for (int j = 0; j < 4; j++)
                s += *(const f32x4*)&part[(((qh << 2) + j) << 8) + (out4 << 2)];
            *(f32x4*)&partR[(qh << 8) + (out4 << 2)] = s;
        }
        __syncthreads();
        // ---- P2 reduce + tanh + blend; publish h ----
        if (tid < 256) {
            float s = 0.f;
            #pragma unroll
            for (int qh = 0; qh < 8; qh++) s += partR[(qh << 8) + (rc << 5) + rb];
            float pre = axh + s;
            float e2  = __expf(2.f * pre);
            float hh  = 1.f - 2.f / (e2 + 1.f);       // tanh
            float z   = zbuf[rc * 33 + rb];
            float h   = hsave[rc * 33 + rb];
            float hn  = (1.f - z) * h + z * hh;
            stg_coh(hxT + (ch0 + rc) * 32 + rb, hn);
            hnb[rc * 33 + rb] = hn;
            if (t == S_LEN - 1) hfin[rb * HID + ch0 + rc] = hn;
        }
        bar_arrive(flags, bid, bc);

        // ============ inside h-barrier window: hseq + ax prefetch ==========
        if (tid < 256) {
            const int c2 = tid & 7, b2 = tid >> 3;
            hseq[(size_t)((t << 5) + b2) * HID + ch0 + c2] = hnb[c2 * 33 + b2];
            if (t + 1 < S_LEN) {
                const size_t o = (size_t)((t + 1) << 5) + rb;
                axr = axT[(size_t)(       ch0 + rc) * MROWS + o];
                axz = axT[(size_t)( 512 + ch0 + rc) * MROWS + o];
                axh = axT[(size_t)(1024 + ch0 + rc) * MROWS + o];
            }
        }
        // ===================================================================
        bar_wait(flags, bc); bc++;
    }
}

// ---------------------------------------------------------------------------
extern "C" void kernel_launch(void* const* d_in, const int* in_sizes, int n_in,
                              void* d_out, int out_size, void* d_ws, size_t ws_size,
                              hipStream_t stream)
{
    const int*   tokens = (const int*)  d_in[0];   // [S,B]
    const float* h0     = (const float*)d_in[1];   // [L,B,H]
    const float* emb    = (const float*)d_in[2];   // [V,H]
    const float* Wx     = (const float*)d_in[3];   // [L,3,H,H]
    const float* bx     = (const float*)d_in[4];   // [L,3,H]
    const float* U      = (const float*)d_in[5];   // [L,3,H,H]
    const float* Wy     = (const float*)d_in[6];   // [V,H]
    const float* by     = (const float*)d_in[7];   // [V]
    float*       out    = (float*)d_out;

    // workspace: axT [1536*4096] (transposed); hseq [4096*512]
    float* ws    = (float*)d_ws;
    float* axT   = ws;
    float* hseq  = axT + (size_t)1536 * MROWS;

    const size_t logits_sz = (size_t)MROWS * VOCAB;
    float* hfin0 = out + logits_sz;
    float* hfin1 = out + logits_sz + BATCH * HID;

    // scratch carved from the logits region (overwritten by the final GEMM):
    float*    vT    = out;                         // [512][32]
    float*    hxT   = out + 16384;                 // [512][32]
    unsigned* flags = (unsigned*)(out + 32768);
    hipMemsetAsync(flags, 0, 2 * NBLK * sizeof(unsigned), stream);

    // axT0 = (emb[tokens] @ Wx[0] + bx[0])^T   [1536][4096]
    gemm_kernel<true, true, true><<<dim3(1536 / 64, MROWS / 64), 256, 0, stream>>>(
        emb, tokens, Wx, bx, axT, MROWS, 1536, HID);

    // layer-0 scan
    scan_coop_kernel<<<NBLK, NTHR, 0, stream>>>(
        axT, U, h0, hseq, hfin0, vT, hxT, flags);

    // axT1 = (hseq @ Wx[1] + bx[1])^T
    gemm_kernel<false, true, true><<<dim3(1536 / 64, MROWS / 64), 256, 0, stream>>>(
        hseq, nullptr, Wx + 3 * HH, bx + 1536, axT, MROWS, 1536, HID);

    // layer-1 scan
    scan_coop_kernel<<<NBLK, NTHR, 0, stream>>>(
        axT, U + 3 * HH, h0 + BATCH * HID, hseq, hfin1, vT, hxT, flags + NBLK);

    // logits = tops @ Wy^T + by   (128x128 tile)
    gemm128_kernel<<<dim3((VOCAB + 127) / 128, MROWS / 128), 256, 0, stream>>>(
        hseq, Wy, by, out, MROWS, VOCAB, HID);
}